// Round 3
// baseline (29.566 us; speedup 1.0000x reference)
//
#include <hip/hip_runtime.h>

// TwoBodySplineScalarEmbed: out[e,c] = sum_b basis(x[e])_b * coeffs[cls[e], b, c]
// Quadratic uniform B-spline on [0,1], grid=5, NUM_BASIS=6; only 3 weights nonzero:
//   i0 = clamp(floor(4x),0,3), u = 4x-i0
//   w0 = (1-u)^2/2, w1 = -u^2+u+1/2, w2 = u^2/2   at basis rows i0..i0+2
constexpr int NUM_TYPES  = 4;
constexpr int NUM_BASIS  = 6;
constexpr int CHANNELS   = 64;
constexpr int NROWS      = NUM_TYPES * NUM_TYPES * NUM_BASIS;   // 96 rows
// Pad LDS row stride 64 -> 68 floats: row base banks shift by 4*(row%8),
// breaking the 8-way cross-group ds_read_b128 bank conflict (all-rows-mod-32==0).
constexpr int ROW_STRIDE = CHANNELS + 4;                        // 68
constexpr int LDS_FLOATS = NROWS * ROW_STRIDE;                  // 6528 (25.5 KiB)

typedef float f4 __attribute__((ext_vector_type(4)));
typedef int   i4 __attribute__((ext_vector_type(4)));

__global__ __launch_bounds__(256)
void TwoBodySplineScalarEmbed_kernel(const float* __restrict__ x,
                                     const int*   __restrict__ edge_types,
                                     const float* __restrict__ coeffs,
                                     float*       __restrict__ out,
                                     int E)
{
    __shared__ float sc[LDS_FLOATS];
    for (int i = threadIdx.x; i < NROWS * CHANNELS; i += 256) {
        int row = i >> 6, col = i & 63;
        sc[row * ROW_STRIDE + col] = coeffs[i];
    }
    __syncthreads();

    const int laneC = threadIdx.x & 15;   // which float4 of the 64 channels
    const int grp   = threadIdx.x >> 4;   // 0..15: edge-group within block
    const int c0    = laneC * 4;

    // Each group handles 4 consecutive edges per iteration -> 64 edges/block-iter.
    for (int e0 = blockIdx.x * 64 + grp * 4; e0 < E; e0 += gridDim.x * 64)
    {
        if (e0 + 3 < E) {
            // Vectorized inputs (e0 % 4 == 0, E % 4 == 0 -> 16B aligned)
            f4 xv = *reinterpret_cast<const f4*>(x + e0);
            i4 tc = *reinterpret_cast<const i4*>(edge_types + e0);
            i4 tn = *reinterpret_cast<const i4*>(edge_types + E + e0);

            #pragma unroll
            for (int j = 0; j < 4; ++j) {
                float xj = fminf(fmaxf(xv[j], 0.0f), 1.0f - 1e-6f);
                float s  = xj * 4.0f;
                int   i0 = (int)s;  i0 = i0 > 3 ? 3 : i0;
                float u  = s - (float)i0;
                float omu = 1.0f - u;
                float w0 = 0.5f * omu * omu;
                float w1 = u * omu + 0.5f;
                float w2 = 0.5f * u * u;

                int row = (tc[j] * NUM_TYPES + tn[j]) * NUM_BASIS + i0;
                const float* base = &sc[row * ROW_STRIDE + c0];
                f4 r0 = *reinterpret_cast<const f4*>(base);
                f4 r1 = *reinterpret_cast<const f4*>(base + ROW_STRIDE);
                f4 r2 = *reinterpret_cast<const f4*>(base + 2 * ROW_STRIDE);

                f4 o = w0 * r0 + w1 * r1 + w2 * r2;
                __builtin_nontemporal_store(
                    o, reinterpret_cast<f4*>(out + (size_t)(e0 + j) * CHANNELS + c0));
            }
        } else {
            // Ragged tail (E not a multiple of 64): scalar-per-edge path.
            for (int j = 0; j < 4; ++j) {
                int e = e0 + j;
                if (e >= E) break;
                float xj = fminf(fmaxf(x[e], 0.0f), 1.0f - 1e-6f);
                float s  = xj * 4.0f;
                int   i0 = (int)s;  i0 = i0 > 3 ? 3 : i0;
                float u  = s - (float)i0;
                float omu = 1.0f - u;
                float w0 = 0.5f * omu * omu;
                float w1 = u * omu + 0.5f;
                float w2 = 0.5f * u * u;

                int row = (edge_types[e] * NUM_TYPES + edge_types[E + e]) * NUM_BASIS + i0;
                const float* base = &sc[row * ROW_STRIDE + c0];
                f4 r0 = *reinterpret_cast<const f4*>(base);
                f4 r1 = *reinterpret_cast<const f4*>(base + ROW_STRIDE);
                f4 r2 = *reinterpret_cast<const f4*>(base + 2 * ROW_STRIDE);

                f4 o = w0 * r0 + w1 * r1 + w2 * r2;
                __builtin_nontemporal_store(
                    o, reinterpret_cast<f4*>(out + (size_t)e * CHANNELS + c0));
            }
        }
    }
}

extern "C" void kernel_launch(void* const* d_in, const int* in_sizes, int n_in,
                              void* d_out, int out_size, void* d_ws, size_t ws_size,
                              hipStream_t stream)
{
    const float* x          = (const float*)d_in[0];
    const int*   edge_types = (const int*)d_in[1];
    const float* coeffs     = (const float*)d_in[2];
    float*       out        = (float*)d_out;

    const int E = in_sizes[0];

    // 25.5 KiB LDS/block -> 6 blocks/CU resident; 256 CU * 6 = 1536 all co-resident.
    int grid = (E + 63) / 64;
    if (grid > 1536) grid = 1536;

    TwoBodySplineScalarEmbed_kernel<<<grid, 256, 0, stream>>>(
        x, edge_types, coeffs, out, E);
}

// Round 4
// 28.054 us; speedup vs baseline: 1.0539x; 1.0539x over previous
//
#include <hip/hip_runtime.h>

// TwoBodySplineScalarEmbed: out[e,c] = sum_b basis(x[e])_b * coeffs[cls[e], b, c]
// Quadratic uniform B-spline on [0,1], grid=5, NUM_BASIS=6; only 3 weights nonzero:
//   i0 = clamp(floor(4x),0,3), u = 4x-i0
//   w0 = (1-u)^2/2, w1 = -u^2+u+1/2, w2 = u^2/2   at basis rows i0..i0+2
constexpr int NUM_TYPES    = 4;
constexpr int NUM_BASIS    = 6;
constexpr int CHANNELS     = 64;
constexpr int COEFF_FLOATS = NUM_TYPES * NUM_TYPES * NUM_BASIS * CHANNELS; // 6144 (24 KiB)

typedef float f4 __attribute__((ext_vector_type(4)));
typedef int   i4 __attribute__((ext_vector_type(4)));

__global__ __launch_bounds__(256)
void TwoBodySplineScalarEmbed_kernel(const float* __restrict__ x,
                                     const int*   __restrict__ edge_types,
                                     const float* __restrict__ coeffs,
                                     float*       __restrict__ out,
                                     int E)
{
    __shared__ float sc[COEFF_FLOATS];
    for (int i = threadIdx.x; i < COEFF_FLOATS; i += 256)
        sc[i] = coeffs[i];
    __syncthreads();

    const int laneC = threadIdx.x & 15;   // which float4 of the 64 channels
    const int grp   = threadIdx.x >> 4;   // 0..15: edge-group within block
    const int c0    = laneC * 4;
    const int stride = gridDim.x * 64;

    int e0 = blockIdx.x * 64 + grp * 4;

    if ((E & 3) == 0) {
        // E multiple of 4 -> every in-range e0 has a full float4 of edges.
        f4 xv; i4 tc, tn;
        if (e0 < E) {
            xv = *reinterpret_cast<const f4*>(x + e0);
            tc = *reinterpret_cast<const i4*>(edge_types + e0);
            tn = *reinterpret_cast<const i4*>(edge_types + E + e0);
        }
        for (; e0 < E; ) {
            const int e1 = e0 + stride;
            // Software-prefetch next iteration's inputs (hide HBM latency).
            f4 xv_n; i4 tc_n, tn_n;
            if (e1 < E) {
                xv_n = *reinterpret_cast<const f4*>(x + e1);
                tc_n = *reinterpret_cast<const i4*>(edge_types + e1);
                tn_n = *reinterpret_cast<const i4*>(edge_types + E + e1);
            }

            #pragma unroll
            for (int j = 0; j < 4; ++j) {
                float xj = fminf(fmaxf(xv[j], 0.0f), 1.0f - 1e-6f);
                float s  = xj * 4.0f;
                int   i0 = (int)s;  i0 = i0 > 3 ? 3 : i0;
                float u  = s - (float)i0;
                float omu = 1.0f - u;
                float w0 = 0.5f * omu * omu;
                float w1 = u * omu + 0.5f;
                float w2 = 0.5f * u * u;

                int cls = tc[j] * NUM_TYPES + tn[j];
                const float* base = &sc[(cls * NUM_BASIS + i0) * CHANNELS + c0];
                f4 r0 = *reinterpret_cast<const f4*>(base);
                f4 r1 = *reinterpret_cast<const f4*>(base + CHANNELS);
                f4 r2 = *reinterpret_cast<const f4*>(base + 2 * CHANNELS);

                f4 o = w0 * r0 + w1 * r1 + w2 * r2;
                *reinterpret_cast<f4*>(out + (size_t)(e0 + j) * CHANNELS + c0) = o;
            }

            xv = xv_n; tc = tc_n; tn = tn_n;
            e0 = e1;
        }
    } else {
        // Generic path (unused for E % 4 == 0): per-edge scalar.
        for (; e0 < E; e0 += stride) {
            for (int j = 0; j < 4; ++j) {
                int e = e0 + j;
                if (e >= E) break;
                float xj = fminf(fmaxf(x[e], 0.0f), 1.0f - 1e-6f);
                float s  = xj * 4.0f;
                int   i0 = (int)s;  i0 = i0 > 3 ? 3 : i0;
                float u  = s - (float)i0;
                float omu = 1.0f - u;
                float w0 = 0.5f * omu * omu;
                float w1 = u * omu + 0.5f;
                float w2 = 0.5f * u * u;

                int cls = edge_types[e] * NUM_TYPES + edge_types[E + e];
                const float* base = &sc[(cls * NUM_BASIS + i0) * CHANNELS + c0];
                f4 r0 = *reinterpret_cast<const f4*>(base);
                f4 r1 = *reinterpret_cast<const f4*>(base + CHANNELS);
                f4 r2 = *reinterpret_cast<const f4*>(base + 2 * CHANNELS);

                f4 o = w0 * r0 + w1 * r1 + w2 * r2;
                *reinterpret_cast<f4*>(out + (size_t)e * CHANNELS + c0) = o;
            }
        }
    }
}

extern "C" void kernel_launch(void* const* d_in, const int* in_sizes, int n_in,
                              void* d_out, int out_size, void* d_ws, size_t ws_size,
                              hipStream_t stream)
{
    const float* x          = (const float*)d_in[0];
    const int*   edge_types = (const int*)d_in[1];
    const float* coeffs     = (const float*)d_in[2];
    float*       out        = (float*)d_out;

    const int E = in_sizes[0];

    // 24 KiB LDS/block -> 6 blocks/CU resident; 256 CU * 6 = 1536 all co-resident.
    int grid = (E + 63) / 64;
    if (grid > 1536) grid = 1536;

    TwoBodySplineScalarEmbed_kernel<<<grid, 256, 0, stream>>>(
        x, edge_types, coeffs, out, E);
}

// Round 5
// 27.736 us; speedup vs baseline: 1.0660x; 1.0115x over previous
//
#include <hip/hip_runtime.h>

// TwoBodySplineScalarEmbed: out[e,c] = sum_b basis(x[e])_b * coeffs[cls[e], b, c]
// Quadratic uniform B-spline on [0,1], grid=5, NUM_BASIS=6; only 3 weights nonzero:
//   i0 = clamp(floor(4x),0,3), u = 4x-i0
//   w0 = (1-u)^2/2, w1 = -u^2+u+1/2, w2 = u^2/2   at basis rows i0..i0+2
//
// Work quantum = 1 edge per 16-lane group (grid-stride). With 1536 blocks the
// per-worker iteration count is 20-21 (3.2% imbalance) vs 5-6 (18%) for the
// old 64-edge block quantum — that imbalance was the R1-R3 28µs plateau.
constexpr int NUM_TYPES    = 4;
constexpr int NUM_BASIS    = 6;
constexpr int CHANNELS     = 64;
constexpr int COEFF_FLOATS = NUM_TYPES * NUM_TYPES * NUM_BASIS * CHANNELS; // 6144 (24 KiB)

typedef float f4 __attribute__((ext_vector_type(4)));

__global__ __launch_bounds__(256)
void TwoBodySplineScalarEmbed_kernel(const float* __restrict__ x,
                                     const int*   __restrict__ edge_types,
                                     const float* __restrict__ coeffs,
                                     float*       __restrict__ out,
                                     int E)
{
    __shared__ float sc[COEFF_FLOATS];
    // Vectorized cooperative stage: 6144 floats = 1536 f4 = 256 threads x 6.
    #pragma unroll
    for (int i = 0; i < COEFF_FLOATS / 4 / 256; ++i) {
        int idx = threadIdx.x + i * 256;
        reinterpret_cast<f4*>(sc)[idx] = reinterpret_cast<const f4*>(coeffs)[idx];
    }
    __syncthreads();

    const int laneC  = threadIdx.x & 15;   // which float4 of the 64 channels
    const int grp    = threadIdx.x >> 4;   // 0..15: group index within block
    const int c0     = laneC * 4;
    const int stride = gridDim.x << 4;     // total groups in grid

    for (int e = (blockIdx.x << 4) + grp; e < E; e += stride)
    {
        float xj = fminf(fmaxf(x[e], 0.0f), 1.0f - 1e-6f);
        float s  = xj * 4.0f;
        int   i0 = (int)s;  i0 = i0 > 3 ? 3 : i0;
        float u  = s - (float)i0;
        float omu = 1.0f - u;
        float w0 = 0.5f * omu * omu;
        float w1 = u * omu + 0.5f;
        float w2 = 0.5f * u * u;

        int row = (edge_types[e] * NUM_TYPES + edge_types[E + e]) * NUM_BASIS + i0;
        const float* base = &sc[row * CHANNELS + c0];
        f4 r0 = *reinterpret_cast<const f4*>(base);
        f4 r1 = *reinterpret_cast<const f4*>(base + CHANNELS);
        f4 r2 = *reinterpret_cast<const f4*>(base + 2 * CHANNELS);

        f4 o = w0 * r0 + w1 * r1 + w2 * r2;
        *reinterpret_cast<f4*>(out + (size_t)e * CHANNELS + c0) = o;
    }
}

extern "C" void kernel_launch(void* const* d_in, const int* in_sizes, int n_in,
                              void* d_out, int out_size, void* d_ws, size_t ws_size,
                              hipStream_t stream)
{
    const float* x          = (const float*)d_in[0];
    const int*   edge_types = (const int*)d_in[1];
    const float* coeffs     = (const float*)d_in[2];
    float*       out        = (float*)d_out;

    const int E = in_sizes[0];

    // 24 KiB LDS/block -> 6 blocks/CU resident; 256 CU * 6 = 1536 all co-resident.
    int grid = (E + 15) / 16;
    if (grid > 1536) grid = 1536;

    TwoBodySplineScalarEmbed_kernel<<<grid, 256, 0, stream>>>(
        x, edge_types, coeffs, out, E);
}

// Round 6
// 27.019 us; speedup vs baseline: 1.0943x; 1.0266x over previous
//
#include <hip/hip_runtime.h>

// TwoBodySplineScalarEmbed: out[e,c] = sum_b basis(x[e])_b * coeffs[cls[e], b, c]
// Quadratic uniform B-spline on [0,1], grid=5, NUM_BASIS=6; only 3 weights nonzero:
//   i0 = clamp(floor(4x),0,3), u = 4x-i0
//   w0 = (1-u)^2/2, w1 = -u^2+u+1/2, w2 = u^2/2   at basis rows i0..i0+2
//
// R5 theory: eliminate HBM read/write turnaround in the steady state.
// All per-edge inputs for a block's entire work are pre-staged to LDS in one
// coalesced burst; the main loop is then a pure store stream (LDS -> global).
constexpr int NUM_TYPES    = 4;
constexpr int NUM_BASIS    = 6;
constexpr int CHANNELS     = 64;
constexpr int COEFF_FLOATS = NUM_TYPES * NUM_TYPES * NUM_BASIS * CHANNELS; // 6144 (24 KiB)
constexpr int KMAX  = 21;          // max inner iterations per staging pass
constexpr int SLOTS = 16 * KMAX;   // 336 edges staged per block per pass

typedef float f4 __attribute__((ext_vector_type(4)));

__global__ __launch_bounds__(256)
void TwoBodySplineScalarEmbed_kernel(const float* __restrict__ x,
                                     const int*   __restrict__ edge_types,
                                     const float* __restrict__ coeffs,
                                     float*       __restrict__ out,
                                     int E)
{
    __shared__ float          sc[COEFF_FLOATS];
    __shared__ float          sx[SLOTS];
    __shared__ unsigned short srow[SLOTS];   // cls * NUM_BASIS (fits in u16)
    // total LDS: 24576 + 1344 + 672 = 26592 B -> still 6 blocks/CU

    // Stage coefficient table (vectorized: 1536 f4 = 256 threads x 6).
    #pragma unroll
    for (int i = 0; i < COEFF_FLOATS / 4 / 256; ++i) {
        int idx = threadIdx.x + i * 256;
        reinterpret_cast<f4*>(sc)[idx] = reinterpret_cast<const f4*>(coeffs)[idx];
    }

    const int laneC  = threadIdx.x & 15;   // which float4 of the 64 channels
    const int grp    = threadIdx.x >> 4;   // 0..15: group index within block
    const int c0     = laneC * 4;
    const int stride = gridDim.x << 4;     // edges consumed per inner iteration
    const int t      = threadIdx.x;

    for (int base = blockIdx.x << 4; base < E; base += stride * KMAX)
    {
        // Stage this pass's inputs: slot s = k*16 + g  ->  edge = base + g + k*stride.
        for (int s = t; s < SLOTS; s += 256) {
            int e = base + (s & 15) + (s >> 4) * stride;
            if (e < E) {
                sx[s]   = x[e];
                srow[s] = (unsigned short)((edge_types[e] * NUM_TYPES +
                                            edge_types[E + e]) * NUM_BASIS);
            }
        }
        __syncthreads();

        // Pure-store main loop: only LDS reads + global stores.
        for (int k = 0; k < KMAX; ++k) {
            int e = base + grp + k * stride;
            if (e >= E) break;
            int s = (k << 4) + grp;

            float xj = fminf(fmaxf(sx[s], 0.0f), 1.0f - 1e-6f);
            float sx4 = xj * 4.0f;
            int   i0  = (int)sx4;  i0 = i0 > 3 ? 3 : i0;
            float u   = sx4 - (float)i0;
            float omu = 1.0f - u;
            float w0 = 0.5f * omu * omu;
            float w1 = u * omu + 0.5f;
            float w2 = 0.5f * u * u;

            const float* bp = &sc[(srow[s] + i0) * CHANNELS + c0];
            f4 r0 = *reinterpret_cast<const f4*>(bp);
            f4 r1 = *reinterpret_cast<const f4*>(bp + CHANNELS);
            f4 r2 = *reinterpret_cast<const f4*>(bp + 2 * CHANNELS);

            f4 o = w0 * r0 + w1 * r1 + w2 * r2;
            *reinterpret_cast<f4*>(out + (size_t)e * CHANNELS + c0) = o;
        }
        __syncthreads();   // protect sx/srow before next pass overwrites (multi-pass only)
    }
}

extern "C" void kernel_launch(void* const* d_in, const int* in_sizes, int n_in,
                              void* d_out, int out_size, void* d_ws, size_t ws_size,
                              hipStream_t stream)
{
    const float* x          = (const float*)d_in[0];
    const int*   edge_types = (const int*)d_in[1];
    const float* coeffs     = (const float*)d_in[2];
    float*       out        = (float*)d_out;

    const int E = in_sizes[0];

    // 26.0 KiB LDS/block -> 6 blocks/CU resident; 256 CU * 6 = 1536 co-resident.
    int grid = (E + 15) / 16;
    if (grid > 1536) grid = 1536;

    TwoBodySplineScalarEmbed_kernel<<<grid, 256, 0, stream>>>(
        x, edge_types, coeffs, out, E);
}